// Round 2
// baseline (671.952 us; speedup 1.0000x reference)
//
#include <hip/hip_runtime.h>
#include <stdint.h>

// ---------------------------------------------------------------------------
// Binary (sign) weight 3-layer MLP, round 8:
//   gemm1: h1 = relu(X_f32 @ sign(W1)^T + b1) -> bf16 [65536,1024]
//          (fp32->bf16 conversion FUSED into A-staging; convert_x deleted)
//   gemm2: h2 = relu(h1 @ sign(W2)^T + b2) -> bf16 [65536,512]
//   gemm3: out = h2 @ sign(W3)^T + b3      -> f32  [65536,10]
// R8 changes vs R7 (R7 post-mortem: swizzle killed bank conflicts, fetch
// -2.4x, but dur flat at 650 TF -> loop not LDS/fetch-bound; WRITE 294MB vs
// 134 ideal; convert_x ~60us of pure traffic):
//   1. convert_x fused into gemm1: A staged reg-side (4 float4 in flight,
//      T14 issue-early/write-late), cvt via v_cvt_pk_bf16_f32, ds_write
//      into the swizzled A-buffer after the buffer-free gate.
//   2. Vectorized epilogue: acc -> LDS (bf16, chunk-swizzled 256x256) ->
//      b128 coalesced full-line stores. Kills the 2.2x write amplification.
//   3. Barriers 4 -> 2 per K-tile (only buffer-free gate + end-of-tile are
//      load-bearing); cluster order tuned so read latency hides under MFMA.
// ---------------------------------------------------------------------------

typedef __attribute__((ext_vector_type(8))) short bf16x8;
typedef __attribute__((ext_vector_type(4))) float f32x4;

typedef const __attribute__((address_space(1))) unsigned int* as1_u32p;
typedef __attribute__((address_space(3))) unsigned int* as3_u32p;

__device__ __forceinline__ void glds16(const void* g, void* l) {
  __builtin_amdgcn_global_load_lds((as1_u32p)g, (as3_u32p)l, 16, 0, 0);
}

__device__ __forceinline__ unsigned short f2bf(float f) {
  union { float f; unsigned u; } c;
  c.f = f;
  unsigned u = c.u;
  u += 0x7FFFu + ((u >> 16) & 1u);  // RTNE
  return (unsigned short)(u >> 16);
}

// ---------------------------------------------------------------------------
__global__ void binarize_kernel(const float* __restrict__ src, int Ns, int Ks,
                                short* __restrict__ dst, int Np, int Kp) {
  int idx = blockIdx.x * 256 + threadIdx.x;
  if (idx >= Np * Kp) return;
  int n = idx / Kp;
  int k = idx - n * Kp;
  short v = 0;
  if (n < Ns && k < Ks)
    v = (src[n * Ks + k] >= 0.0f) ? (short)0x3F80 : (short)0xBF80;
  dst[idx] = v;
}

// ---------------------------------------------------------------------------
// gemm1 fused: X f32 [65536,784] x W1b bf16 [1024,832] -> relu bf16 [65536,1024]
// 256x256 tile, BK=64, 8 waves. A: reg-staged f32->bf16 (cvt_pk) with
// swizzled ds_write; B: glds16 with pre-swizzled global source.
// ---------------------------------------------------------------------------
__global__ __launch_bounds__(512, 2)
void gemm1_fused256(const float* __restrict__ X, const short* __restrict__ Wb,
                    const float* __restrict__ bias, short* __restrict__ Hout) {
  constexpr int XK = 784, KPB = 832, NKT = 13, NP = 1024, NR = 1000, NT = 4;
  __shared__ short LB[65536];  // [2][256][64] A | [2][256][64] B  (128 KiB)

  constexpr int NWG8 = (256 * NT) >> 3;
  const int d = blockIdx.x;
  const int lid = (d & 7) * NWG8 + (d >> 3);
  const int mi = lid / NT;
  const int ni = lid - mi * NT;
  const int m0 = mi << 8;
  const int n0 = ni << 8;
  const int start = (ni * NKT) / NT;

  const int tid = threadIdx.x;
  const int lane = tid & 63;
  const int w = tid >> 6;
  const int wm = w >> 2;
  const int wn = w & 3;
  const int l15 = lane & 15;
  const int quad = lane >> 4;

  // --- B staging (glds, swizzled global source; R7-verified layout) ---
  const int srow = (w << 3) + (lane >> 3);
  const int scol = ((lane & 7) ^ (lane >> 3)) << 3;
  const short* bg = Wb + (size_t)(n0 + srow) * KPB + scol;
  short* const lbW = LB + 32768 + (w << 9);
  auto stageB = [&](int pb, int kit) {
    const short* s = bg + kit * 64;
    short* dst = lbW + (pb << 14);
    glds16(s, dst);
    glds16(s + (size_t)64 * KPB, dst + 4096);
    glds16(s + (size_t)128 * KPB, dst + 8192);
    glds16(s + (size_t)192 * KPB, dst + 12288);
  };

  // --- A staging (reg): thread covers row tid>>1, 32-col f32 half (tid&1) ---
  const int arw = tid >> 1;                 // local row 0..255
  const float* xrow = X + (size_t)(m0 + arw) * XK;
  float4 dA[4];
  auto loadA = [&](int kit, int h) {
    const int kb = kit * 64 + ((tid & 1) << 5) + (h << 4);
#pragma unroll
    for (int q = 0; q < 4; ++q) {
      if (kb + q * 4 < XK)
        dA[q] = *(const float4*)(xrow + kb + q * 4);
      else
        dA[q] = make_float4(0.f, 0.f, 0.f, 0.f);
    }
  };
  auto cvtwrA = [&](int pb, int h) {
    unsigned pk[8];
#pragma unroll
    for (int q = 0; q < 4; ++q) {
      asm("v_cvt_pk_bf16_f32 %0, %1, %2" : "=v"(pk[2 * q]) : "v"(dA[q].x), "v"(dA[q].y));
      asm("v_cvt_pk_bf16_f32 %0, %1, %2" : "=v"(pk[2 * q + 1]) : "v"(dA[q].z), "v"(dA[q].w));
    }
    short* ar = LB + (pb << 14) + (arw << 6);
    const int c0 = ((tid & 1) << 2) + (h << 1);
    *(uint4*)(ar + (((c0) ^ (arw & 7)) << 3)) = make_uint4(pk[0], pk[1], pk[2], pk[3]);
    *(uint4*)(ar + (((c0 + 1) ^ (arw & 7)) << 3)) = make_uint4(pk[4], pk[5], pk[6], pk[7]);
  };

  // --- fragment read offsets (R7-verified swizzled layout) ---
  const int arow = ((wm << 7) + l15) << 6;
  const int brow = ((wn << 6) + l15) << 6;
  const int sl0 = (quad ^ (lane & 7)) << 3;
  const int sl1 = sl0 ^ 32;

  f32x4 acc[8][4];
#pragma unroll
  for (int i = 0; i < 8; ++i)
#pragma unroll
    for (int j = 0; j < 4; ++j) acc[i][j] = (f32x4){0.f, 0.f, 0.f, 0.f};

  // --- prologue: fully stage tiles start, start+1 ---
  int kt1 = start + 1; if (kt1 >= NKT) kt1 -= NKT;
  loadA(start, 0);
  asm volatile("s_waitcnt vmcnt(0)" ::: "memory");
  cvtwrA(0, 0);
  loadA(start, 1); stageB(0, start);
  asm volatile("s_waitcnt vmcnt(4)" ::: "memory");  // A(t0,h1) done; B(t0) out
  cvtwrA(0, 1);
  loadA(kt1, 0); stageB(1, kt1);
  asm volatile("s_waitcnt vmcnt(4)" ::: "memory");  // B(t0)+A(t1,h0) done
  cvtwrA(1, 0);
  loadA(kt1, 1);
  asm volatile("s_waitcnt vmcnt(0)" ::: "memory");  // everything staged/landed
  cvtwrA(1, 1);
  asm volatile("s_waitcnt lgkmcnt(0)" ::: "memory");
  __builtin_amdgcn_s_barrier();

  for (int it = 0; it < NKT; ++it) {
    const int pb = it & 1;
    const short* Ab = LB + (pb << 14);
    const short* Bb = LB + 32768 + (pb << 14);
    int kit2 = start + it + 2; if (kit2 >= NKT) kit2 -= NKT;
    const bool stg = (it + 2 < NKT);

    bf16x8 a0[8], b0[4], a1[8], b1[4];
    // P0: read ks0 frags; issue A-H0(it+2); MFMA cluster0
#pragma unroll
    for (int i = 0; i < 8; ++i) a0[i] = *(const bf16x8*)(Ab + arow + i * 1024 + sl0);
#pragma unroll
    for (int j = 0; j < 4; ++j) b0[j] = *(const bf16x8*)(Bb + brow + j * 1024 + sl0);
    if (stg) loadA(kit2, 0);
    __builtin_amdgcn_s_setprio(1);
#pragma unroll
    for (int i = 0; i < 4; ++i)
#pragma unroll
      for (int j = 0; j < 4; ++j)
        acc[i][j] = __builtin_amdgcn_mfma_f32_16x16x32_bf16(a0[i], b0[j], acc[i][j], 0, 0, 0);
    __builtin_amdgcn_s_setprio(0);

    // P1: read ks1 frags; MFMA cluster1; buffer-free gate
#pragma unroll
    for (int i = 0; i < 8; ++i) a1[i] = *(const bf16x8*)(Ab + arow + i * 1024 + sl1);
#pragma unroll
    for (int j = 0; j < 4; ++j) b1[j] = *(const bf16x8*)(Bb + brow + j * 1024 + sl1);
    __builtin_amdgcn_s_setprio(1);
#pragma unroll
    for (int i = 4; i < 8; ++i)
#pragma unroll
      for (int j = 0; j < 4; ++j)
        acc[i][j] = __builtin_amdgcn_mfma_f32_16x16x32_bf16(a0[i], b0[j], acc[i][j], 0, 0, 0);
    __builtin_amdgcn_s_setprio(0);
    asm volatile("s_waitcnt lgkmcnt(0)" ::: "memory");  // my buf[pb] reads done
    __builtin_amdgcn_s_barrier();                       // all waves done

    // P2: A-H0 landed (and stale B(it+1) drained); cvt+write; issue H1; MFMA
    asm volatile("s_waitcnt vmcnt(0)" ::: "memory");
    if (stg) {
      cvtwrA(pb, 0);
      loadA(kit2, 1);
    }
    __builtin_amdgcn_s_setprio(1);
#pragma unroll
    for (int i = 0; i < 4; ++i)
#pragma unroll
      for (int j = 0; j < 4; ++j)
        acc[i][j] = __builtin_amdgcn_mfma_f32_16x16x32_bf16(a1[i], b1[j], acc[i][j], 0, 0, 0);
    __builtin_amdgcn_s_setprio(0);

    // P3: A-H1 landed; cvt+write; stage B(it+2); MFMA; publish
    if (stg) {
      asm volatile("s_waitcnt vmcnt(0)" ::: "memory");
      cvtwrA(pb, 1);
      stageB(pb, kit2);
    }
    __builtin_amdgcn_s_setprio(1);
#pragma unroll
    for (int i = 4; i < 8; ++i)
#pragma unroll
      for (int j = 0; j < 4; ++j)
        acc[i][j] = __builtin_amdgcn_mfma_f32_16x16x32_bf16(a1[i], b1[j], acc[i][j], 0, 0, 0);
    __builtin_amdgcn_s_setprio(0);
    asm volatile("s_waitcnt lgkmcnt(0)" ::: "memory");  // my ds_writes visible
    __builtin_amdgcn_s_barrier();
  }

  // --- epilogue: acc -> LDS bf16 (chunk-swizzled) -> coalesced b128 stores ---
  short* C = LB;  // 256 x 256 bf16, row = 256 shorts, chunk = 8 shorts
#pragma unroll
  for (int j = 0; j < 4; ++j) {
    const int col = (wn << 6) + (j << 4) + l15;
    const int n = n0 + col;
    const float bv = (n < NR) ? bias[n] : 0.f;
#pragma unroll
    for (int i = 0; i < 8; ++i) {
      const int row0 = (wm << 7) + (i << 4) + (quad << 2);
#pragma unroll
      for (int r = 0; r < 4; ++r) {
        float v = acc[i][j][r] + bv;
        v = v > 0.f ? v : 0.f;
        const int row = row0 + r;
        const int sw = ((((col >> 3) ^ (row & 7))) << 3) | (col & 7);
        C[(row << 8) + sw] = (short)f2bf(v);
      }
    }
  }
  __syncthreads();
  {
    const int row = tid >> 1;
    const int ch = (tid & 1) << 4;
    short* gout = Hout + (size_t)(m0 + row) * NP + n0;
#pragma unroll
    for (int v2 = 0; v2 < 16; ++v2) {
      const int c = ch + v2;
      const int sc = c ^ (row & 7);
      bf16x8 dv = *(const bf16x8*)(C + (row << 8) + (sc << 3));
      *(bf16x8*)(gout + (c << 3)) = dv;
    }
  }
}

// ---------------------------------------------------------------------------
// gemm2: 256x256 tile, BK=64, 8 waves, glds A+B (bf16 input), 2 barriers/iter,
// vmcnt(8) steady state, vectorized epilogue.
// ---------------------------------------------------------------------------
template <int KP, int NKT, int NP, int NR, int NT>
__global__ __launch_bounds__(512, 2)
void gemm256(const short* __restrict__ A, const short* __restrict__ Wb,
             const float* __restrict__ bias, short* __restrict__ Hout) {
  __shared__ short LB[65536];

  constexpr int NWG8 = (256 * NT) >> 3;
  const int d = blockIdx.x;
  const int lid = (d & 7) * NWG8 + (d >> 3);
  const int mi = lid / NT;
  const int ni = lid - mi * NT;
  const int m0 = mi << 8;
  const int n0 = ni << 8;
  const int start = (ni * NKT) / NT;

  const int tid = threadIdx.x;
  const int lane = tid & 63;
  const int w = tid >> 6;
  const int wm = w >> 2;
  const int wn = w & 3;
  const int l15 = lane & 15;
  const int quad = lane >> 4;

  const int srow = (w << 3) + (lane >> 3);
  const int scol = ((lane & 7) ^ (lane >> 3)) << 3;
  const short* ag = A + (size_t)(m0 + srow) * KP + scol;
  const short* bg = Wb + (size_t)(n0 + srow) * KP + scol;
  short* const la = LB + (w << 9);
  short* const lb = LB + 32768 + (w << 9);

  auto stageA = [&](int pb, int kit) {
    const short* s = ag + kit * 64;
    short* dst = la + (pb << 14);
    glds16(s, dst);
    glds16(s + (size_t)64 * KP, dst + 4096);
    glds16(s + (size_t)128 * KP, dst + 8192);
    glds16(s + (size_t)192 * KP, dst + 12288);
  };
  auto stageB = [&](int pb, int kit) {
    const short* s = bg + kit * 64;
    short* dst = lb + (pb << 14);
    glds16(s, dst);
    glds16(s + (size_t)64 * KP, dst + 4096);
    glds16(s + (size_t)128 * KP, dst + 8192);
    glds16(s + (size_t)192 * KP, dst + 12288);
  };

  const int arow = ((wm << 7) + l15) << 6;
  const int brow = ((wn << 6) + l15) << 6;
  const int sl0 = (quad ^ (lane & 7)) << 3;
  const int sl1 = sl0 ^ 32;

  f32x4 acc[8][4];
#pragma unroll
  for (int i = 0; i < 8; ++i)
#pragma unroll
    for (int j = 0; j < 4; ++j) acc[i][j] = (f32x4){0.f, 0.f, 0.f, 0.f};

  int kt1 = start + 1; if (kt1 >= NKT) kt1 -= NKT;
  stageA(0, start); stageB(0, start);
  stageA(1, kt1);   stageB(1, kt1);
  asm volatile("s_waitcnt vmcnt(8)" ::: "memory");
  __builtin_amdgcn_s_barrier();

  for (int it = 0; it < NKT; ++it) {
    const int pb = it & 1;
    const short* Ab = LB + (pb << 14);
    const short* Bb = LB + 32768 + (pb << 14);
    int kit2 = start + it + 2; if (kit2 >= NKT) kit2 -= NKT;
    const bool stg = (it + 2 < NKT);

    bf16x8 a0[8], b0[4], a1[8], b1[4];
    // P0
#pragma unroll
    for (int i = 0; i < 8; ++i) a0[i] = *(const bf16x8*)(Ab + arow + i * 1024 + sl0);
#pragma unroll
    for (int j = 0; j < 4; ++j) b0[j] = *(const bf16x8*)(Bb + brow + j * 1024 + sl0);
    __builtin_amdgcn_s_setprio(1);
#pragma unroll
    for (int i = 0; i < 4; ++i)
#pragma unroll
      for (int j = 0; j < 4; ++j)
        acc[i][j] = __builtin_amdgcn_mfma_f32_16x16x32_bf16(a0[i], b0[j], acc[i][j], 0, 0, 0);
    __builtin_amdgcn_s_setprio(0);

    // P1
#pragma unroll
    for (int i = 0; i < 8; ++i) a1[i] = *(const bf16x8*)(Ab + arow + i * 1024 + sl1);
#pragma unroll
    for (int j = 0; j < 4; ++j) b1[j] = *(const bf16x8*)(Bb + brow + j * 1024 + sl1);
    __builtin_amdgcn_s_setprio(1);
#pragma unroll
    for (int i = 4; i < 8; ++i)
#pragma unroll
      for (int j = 0; j < 4; ++j)
        acc[i][j] = __builtin_amdgcn_mfma_f32_16x16x32_bf16(a0[i], b0[j], acc[i][j], 0, 0, 0);
    __builtin_amdgcn_s_setprio(0);
    asm volatile("s_waitcnt lgkmcnt(0)" ::: "memory");
    __builtin_amdgcn_s_barrier();

    // P2
    if (stg) stageA(pb, kit2);
    __builtin_amdgcn_s_setprio(1);
#pragma unroll
    for (int i = 0; i < 4; ++i)
#pragma unroll
      for (int j = 0; j < 4; ++j)
        acc[i][j] = __builtin_amdgcn_mfma_f32_16x16x32_bf16(a1[i], b1[j], acc[i][j], 0, 0, 0);
    __builtin_amdgcn_s_setprio(0);

    // P3
    if (stg) stageB(pb, kit2);
    __builtin_amdgcn_s_setprio(1);
#pragma unroll
    for (int i = 4; i < 8; ++i)
#pragma unroll
      for (int j = 0; j < 4; ++j)
        acc[i][j] = __builtin_amdgcn_mfma_f32_16x16x32_bf16(a1[i], b1[j], acc[i][j], 0, 0, 0);
    __builtin_amdgcn_s_setprio(0);
    if (stg) asm volatile("s_waitcnt vmcnt(8)" ::: "memory");
    else     asm volatile("s_waitcnt vmcnt(0)" ::: "memory");
    __builtin_amdgcn_s_barrier();
  }

  // epilogue
  short* C = LB;
#pragma unroll
  for (int j = 0; j < 4; ++j) {
    const int col = (wn << 6) + (j << 4) + l15;
    const int n = n0 + col;
    const float bv = (n < NR) ? bias[n] : 0.f;
#pragma unroll
    for (int i = 0; i < 8; ++i) {
      const int row0 = (wm << 7) + (i << 4) + (quad << 2);
#pragma unroll
      for (int r = 0; r < 4; ++r) {
        float v = acc[i][j][r] + bv;
        v = v > 0.f ? v : 0.f;
        const int row = row0 + r;
        const int sw = ((((col >> 3) ^ (row & 7))) << 3) | (col & 7);
        C[(row << 8) + sw] = (short)f2bf(v);
      }
    }
  }
  __syncthreads();
  {
    const int row = tid >> 1;
    const int ch = (tid & 1) << 4;
    short* gout = Hout + (size_t)(m0 + row) * NP + n0;
#pragma unroll
    for (int v2 = 0; v2 < 16; ++v2) {
      const int c = ch + v2;
      const int sc = c ^ (row & 7);
      bf16x8 dv = *(const bf16x8*)(C + (row << 8) + (sc << 3));
      *(bf16x8*)(gout + (c << 3)) = dv;
    }
  }
}

// ---------------------------------------------------------------------------
// GEMM3: h2 bf16 [65536,512] x W3b [16,512] -> out f32 [65536,10]
// ---------------------------------------------------------------------------
__global__ __launch_bounds__(256, 2)
void gemm3_kernel(const short* __restrict__ Hin, const short* __restrict__ Wb,
                  const float* __restrict__ bias, float* __restrict__ Out) {
  constexpr int KP = 512;
  __shared__ short As[64 * KP];

  const int tid = threadIdx.x;
  const int lane = tid & 63;
  const int wave = tid >> 6;
  const int l15 = lane & 15;
  const int quad = lane >> 4;
  const int m0 = blockIdx.x * 64;

  bf16x8 bw[16];
#pragma unroll
  for (int kk = 0; kk < 16; ++kk)
    bw[kk] = *(const bf16x8*)(Wb + l15 * KP + kk * 32 + quad * 8);

  const short* asrc = Hin + (size_t)(m0 + wave * 16) * KP + lane * 8;
  short* adst = As + (size_t)(wave * 16) * KP;
#pragma unroll
  for (int t = 0; t < 16; ++t)
    glds16(asrc + (size_t)t * KP, adst + (size_t)t * KP);

  __syncthreads();

  f32x4 acc = (f32x4){0.f, 0.f, 0.f, 0.f};
  const short* abase = As + (size_t)(wave * 16 + l15) * KP + quad * 8;
#pragma unroll
  for (int kk = 0; kk < 16; ++kk) {
    bf16x8 af = *(const bf16x8*)(abase + kk * 32);
    acc = __builtin_amdgcn_mfma_f32_16x16x32_bf16(af, bw[kk], acc, 0, 0, 0);
  }

  if (l15 < 10) {
    const float bv = bias[l15];
#pragma unroll
    for (int r = 0; r < 4; ++r) {
      const int mr = m0 + wave * 16 + quad * 4 + r;
      Out[(size_t)mr * 10 + l15] = acc[r] + bv;
    }
  }
}

// ---------------------------------------------------------------------------
extern "C" void kernel_launch(void* const* d_in, const int* in_sizes, int n_in,
                              void* d_out, int out_size, void* d_ws, size_t ws_size,
                              hipStream_t stream) {
  const float* x = (const float*)d_in[0];
  const float* W1 = (const float*)d_in[1];
  const float* b1 = (const float*)d_in[2];
  const float* W2 = (const float*)d_in[3];
  const float* b2 = (const float*)d_in[4];
  const float* W3 = (const float*)d_in[5];
  const float* b3 = (const float*)d_in[6];
  float* out = (float*)d_out;

  const size_t szW1 = (size_t)1024 * 832 * 2;
  const size_t szW2 = (size_t)512 * 1024 * 2;
  const size_t szW3 = (size_t)16 * 512 * 2;
  const size_t szH1 = (size_t)65536 * 1024 * 2;

  uint8_t* p = (uint8_t*)d_ws;
  short* W1b = (short*)p; p += szW1;
  short* W2b = (short*)p; p += szW2;
  short* W3b = (short*)p; p += szW3;
  short* h1 = (short*)p; p += szH1;
  short* h2 = (short*)p;

  binarize_kernel<<<(1024 * 832 + 255) / 256, 256, 0, stream>>>(W1, 1000, 784, W1b, 1024, 832);
  binarize_kernel<<<(512 * 1024 + 255) / 256, 256, 0, stream>>>(W2, 500, 1000, W2b, 512, 1024);
  binarize_kernel<<<(16 * 512 + 255) / 256, 256, 0, stream>>>(W3, 10, 500, W3b, 16, 512);

  gemm1_fused256<<<1024, 512, 0, stream>>>(x, W1b, b1, h1);
  gemm256<1024, 16, 512, 500, 2><<<512, 512, 0, stream>>>(h1, W2b, b2, h2);
  gemm3_kernel<<<1024, 256, 0, stream>>>(h2, W3b, b3, out);
}

// Round 3
// 530.114 us; speedup vs baseline: 1.2676x; 1.2676x over previous
//
#include <hip/hip_runtime.h>
#include <stdint.h>

// ---------------------------------------------------------------------------
// Binary (sign) weight 3-layer MLP, round 9:
//   convert_x: x f32 [65536,784] -> Xp bf16 [65536,832]
//   gemm1: h1 = relu(Xp @ sign(W1)^T + b1) -> bf16 [65536,1024]
//   gemm2: h2 = relu(h1 @ sign(W2)^T + b2) -> bf16 [65536,512]
//   gemm3: out = h2 @ sign(W3)^T + b3      -> f32  [65536,10]
// R9: R8 fusion reverted (reg-staged X + vmcnt(0) drains = 364us disaster).
// R6==R7==650TF showed: counted pipeline (R7) OR TLP (R6) alone both plateau;
// no pipe >40% busy, 1 block/CU means barrier stalls hit all waves at once.
// R9 = BOTH: 128x256 tile, 8 waves, BK=32, dbuf LDS 48KiB, VGPR<=128
// (launch_bounds(512,4)) -> 2 blocks/CU; counted vmcnt(3) steady state,
// 2 barriers/iter, setprio, 2-way-balanced XOR swizzle, XCD swizzle +
// K-phase rotation. Epilogue: j-innermost store order (line-coherent WC).
// ---------------------------------------------------------------------------

typedef __attribute__((ext_vector_type(8))) short bf16x8;
typedef __attribute__((ext_vector_type(4))) float f32x4;

typedef const __attribute__((address_space(1))) unsigned int* as1_u32p;
typedef __attribute__((address_space(3))) unsigned int* as3_u32p;

__device__ __forceinline__ void glds16(const void* g, void* l) {
  __builtin_amdgcn_global_load_lds((as1_u32p)g, (as3_u32p)l, 16, 0, 0);
}

__device__ __forceinline__ unsigned short f2bf(float f) {
  union { float f; unsigned u; } c;
  c.f = f;
  unsigned u = c.u;
  u += 0x7FFFu + ((u >> 16) & 1u);  // RTNE
  return (unsigned short)(u >> 16);
}

// ---------------------------------------------------------------------------
__global__ void binarize_kernel(const float* __restrict__ src, int Ns, int Ks,
                                short* __restrict__ dst, int Np, int Kp) {
  int idx = blockIdx.x * 256 + threadIdx.x;
  if (idx >= Np * Kp) return;
  int n = idx / Kp;
  int k = idx - n * Kp;
  short v = 0;
  if (n < Ns && k < Ks)
    v = (src[n * Ks + k] >= 0.0f) ? (short)0x3F80 : (short)0xBF80;
  dst[idx] = v;
}

// ---------------------------------------------------------------------------
// convert_x: X f32 [65536,784] -> Xp bf16 [65536,832], cols 784..832 zeroed.
// ---------------------------------------------------------------------------
__global__ void convert_x_kernel(const float* __restrict__ X, short* __restrict__ Xp) {
  const int g = blockIdx.x * 256 + threadIdx.x;
  if (g >= 65536 * 104) return;
  const int row = g / 104;
  const int c = (g - row * 104) * 8;
  short tmp[8];
  if (c < 784) {
    const float* s = X + (size_t)row * 784 + c;
    float4 f0 = *(const float4*)s;
    float4 f1 = *(const float4*)(s + 4);
    tmp[0] = (short)f2bf(f0.x); tmp[1] = (short)f2bf(f0.y);
    tmp[2] = (short)f2bf(f0.z); tmp[3] = (short)f2bf(f0.w);
    tmp[4] = (short)f2bf(f1.x); tmp[5] = (short)f2bf(f1.y);
    tmp[6] = (short)f2bf(f1.z); tmp[7] = (short)f2bf(f1.w);
  } else {
#pragma unroll
    for (int i = 0; i < 8; ++i) tmp[i] = 0;
  }
  *(bf16x8*)(Xp + (size_t)row * 832 + c) = *(bf16x8*)(tmp);
}

// ---------------------------------------------------------------------------
// 128(M) x 256(N) tile, BK=32, 8 waves (2M x 4N), wave out 64x64 (acc=64 VGPR).
// LDS: dbuf A[128][32] (8KB x2) + B[256][32] (16KB x2) = 48 KiB -> 2 blocks/CU
// with VGPR<=128 (launch_bounds(512,4)). Counted vmcnt(3), 2 barriers/iter.
// Swizzle: LDS[row][s] = global[row][s ^ ((row>>1)&3)], s = 8-short slot.
// ---------------------------------------------------------------------------
template <int KP, int NKT, int NP, int NR, int NT>
__global__ __launch_bounds__(512, 4)
void gemm128x256(const short* __restrict__ A, const short* __restrict__ Wb,
                 const float* __restrict__ bias, short* __restrict__ Hout) {
  __shared__ short Abuf[2][128 * 32];
  __shared__ short Bbuf[2][256 * 32];

  // XCD swizzle: grid = 512*NT blocks (divisible by 8 -> bijective).
  constexpr int NWG8 = (512 * NT) >> 3;
  const int d = blockIdx.x;
  const int lid = (d & 7) * NWG8 + (d >> 3);
  const int mi = lid / NT;
  const int ni = lid - mi * NT;
  const int m0 = mi << 7;
  const int n0 = ni << 8;
  const int start = (ni * NKT) / NT;  // K-phase rotation

  const int tid = threadIdx.x;
  const int lane = tid & 63;
  const int w = tid >> 6;   // 0..7
  const int wm = w >> 2;    // 0..1  (64 m-rows each)
  const int wn = w & 3;     // 0..3  (64 n-cols each)
  const int l15 = lane & 15;
  const int quad = lane >> 4;

  // --- staging addresses (pre-swizzled global source, linear LDS dest) ---
  const int srow = tid >> 2;                       // 0..127
  const int sslot = tid & 3;
  const int gcol = ((sslot ^ ((srow >> 1) & 3)) << 3);
  const short* ag = A + (size_t)(m0 + srow) * KP + gcol;
  const short* bg = Wb + (size_t)(n0 + srow) * KP + gcol;
  // wave-uniform LDS bases (HW adds lane*16B)
  const int ldsw = w << 9;  // w*512 shorts = w*1024 B (16 rows * 32 shorts)

  auto stageA = [&](int pb, int kit) {
    glds16(ag + kit * 32, &Abuf[pb][ldsw]);
  };
  auto stageB = [&](int pb, int kit) {
    const short* s = bg + kit * 32;
    glds16(s, &Bbuf[pb][ldsw]);
    glds16(s + (size_t)128 * KP, &Bbuf[pb][ldsw + 4096]);
  };

  // --- fragment read offsets (swizzled slot; (row>>1)&3 == (l15>>1)&3) ---
  const int sl = (quad ^ ((l15 >> 1) & 3)) << 3;
  const int abase = ((wm << 6) + l15) * 32 + sl;   // + i*512
  const int bbase = ((wn << 6) + l15) * 32 + sl;   // + j*512

  f32x4 acc[4][4];
#pragma unroll
  for (int i = 0; i < 4; ++i)
#pragma unroll
    for (int j = 0; j < 4; ++j) acc[i][j] = (f32x4){0.f, 0.f, 0.f, 0.f};

  // --- prologue: stage tiles start, start+1 (6 glds), confirm oldest 3 ---
  int kt1 = start + 1; if (kt1 >= NKT) kt1 -= NKT;
  stageA(0, start); stageB(0, start);
  stageA(1, kt1);   stageB(1, kt1);
  asm volatile("s_waitcnt vmcnt(3)" ::: "memory");
  __builtin_amdgcn_s_barrier();

  for (int it = 0; it < NKT; ++it) {
    const int pb = it & 1;
    const short* Ab = &Abuf[pb][0];
    const short* Bb = &Bbuf[pb][0];
    int kit2 = start + it + 2; if (kit2 >= NKT) kit2 -= NKT;
    const bool stg = (it + 2 < NKT);

    bf16x8 af[4], bf[4];
#pragma unroll
    for (int i = 0; i < 4; ++i) af[i] = *(const bf16x8*)(Ab + abase + i * 512);
#pragma unroll
    for (int j = 0; j < 4; ++j) bf[j] = *(const bf16x8*)(Bb + bbase + j * 512);

    // first MFMA half (i=0,1)
    __builtin_amdgcn_s_setprio(1);
#pragma unroll
    for (int i = 0; i < 2; ++i)
#pragma unroll
      for (int j = 0; j < 4; ++j)
        acc[i][j] = __builtin_amdgcn_mfma_f32_16x16x32_bf16(af[i], bf[j], acc[i][j], 0, 0, 0);
    __builtin_amdgcn_s_setprio(0);
    asm volatile("s_waitcnt lgkmcnt(0)" ::: "memory");  // my buf[pb] reads done
    __builtin_amdgcn_s_barrier();                       // all waves done -> buf free

    // stage tile it+2 into buf[pb] under second MFMA half
    if (stg) { stageA(pb, kit2); stageB(pb, kit2); }
    __builtin_amdgcn_s_setprio(1);
#pragma unroll
    for (int i = 2; i < 4; ++i)
#pragma unroll
      for (int j = 0; j < 4; ++j)
        acc[i][j] = __builtin_amdgcn_mfma_f32_16x16x32_bf16(af[i], bf[j], acc[i][j], 0, 0, 0);
    __builtin_amdgcn_s_setprio(0);
    // confirm tile it+1 resident; keep this iter's 3 glds in flight
    if (stg) asm volatile("s_waitcnt vmcnt(3)" ::: "memory");
    else     asm volatile("s_waitcnt vmcnt(0)" ::: "memory");
    __builtin_amdgcn_s_barrier();
  }

  // --- epilogue: j-innermost so both 32B halves of each 64B line are
  // written in adjacent instructions (write-combine friendly) ---
  float bv[4];
#pragma unroll
  for (int j = 0; j < 4; ++j) {
    const int n = n0 + (wn << 6) + (j << 4) + l15;
    bv[j] = (n < NR) ? bias[n] : 0.f;
  }
#pragma unroll
  for (int i = 0; i < 4; ++i) {
#pragma unroll
    for (int r = 0; r < 4; ++r) {
      const int mr = m0 + (wm << 6) + (i << 4) + (quad << 2) + r;
      short* rowp = Hout + (size_t)mr * NP + n0 + (wn << 6) + l15;
#pragma unroll
      for (int j = 0; j < 4; ++j) {
        float v = acc[i][j][r] + bv[j];
        v = v > 0.f ? v : 0.f;
        rowp[j << 4] = (short)f2bf(v);
      }
    }
  }
}

// ---------------------------------------------------------------------------
// Fallback GEMM1 (small-ws): fused fp32->bf16 convert, 128-tile, BK=32.
// ---------------------------------------------------------------------------
__global__ __launch_bounds__(256, 2)
void gemm1_fused_kernel(const float* __restrict__ X, const short* __restrict__ Wb,
                        const float* __restrict__ bias, short* __restrict__ H) {
  constexpr int K = 784, KP = 832, NP = 1024, NR = 1000;
  __shared__ short As[128 * 32];
  __shared__ short Bs[128 * 32];

  const int tid = threadIdx.x;
  const int lane = tid & 63;
  const int wave = tid >> 6;
  const int wm = wave >> 1, wn = wave & 1;
  const int l15 = lane & 15;
  const int quad = lane >> 4;
  const int m0 = blockIdx.y * 128;
  const int n0 = blockIdx.x * 128;

  const int ar = tid >> 1;
  const int aks = (tid & 1) * 16;
  const float* xrow = X + (size_t)(m0 + ar) * K;
  short* adst = As + ar * 32 + aks;

  const int br = wave * 16 + (lane >> 2);
  const int bks = (lane & 3) * 8;
  const short* brow0 = Wb + (size_t)(n0 + br) * KP + bks;
  short* bdst = Bs + (wave * 16) * 32;

  f32x4 acc[4][4];
#pragma unroll
  for (int i = 0; i < 4; ++i)
#pragma unroll
    for (int j2 = 0; j2 < 4; ++j2) acc[i][j2] = (f32x4){0.f, 0.f, 0.f, 0.f};

  for (int k0 = 0; k0 < KP; k0 += 32) {
    glds16(brow0 + k0, bdst);
    glds16(brow0 + k0 + (size_t)64 * KP, bdst + 64 * 32);
    short tmp[16];
#pragma unroll
    for (int c = 0; c < 4; ++c) {
      const int kk = k0 + aks + c * 4;
      float4 f;
      if (kk + 3 < K)
        f = *(const float4*)(xrow + kk);
      else
        f = make_float4(0.f, 0.f, 0.f, 0.f);
      tmp[c * 4 + 0] = (short)f2bf(f.x);
      tmp[c * 4 + 1] = (short)f2bf(f.y);
      tmp[c * 4 + 2] = (short)f2bf(f.z);
      tmp[c * 4 + 3] = (short)f2bf(f.w);
    }
    *(bf16x8*)(adst) = *(bf16x8*)(tmp);
    *(bf16x8*)(adst + 8) = *(bf16x8*)(tmp + 8);
    __syncthreads();

    const short* abase = As + (size_t)(wm * 64 + l15) * 32 + quad * 8;
    const short* bbase = Bs + (size_t)(wn * 64 + l15) * 32 + quad * 8;
    bf16x8 af[4], bfr[4];
#pragma unroll
    for (int i = 0; i < 4; ++i) af[i] = *(const bf16x8*)(abase + i * 16 * 32);
#pragma unroll
    for (int j2 = 0; j2 < 4; ++j2) bfr[j2] = *(const bf16x8*)(bbase + j2 * 16 * 32);
#pragma unroll
    for (int i = 0; i < 4; ++i)
#pragma unroll
      for (int j2 = 0; j2 < 4; ++j2)
        acc[i][j2] = __builtin_amdgcn_mfma_f32_16x16x32_bf16(af[i], bfr[j2], acc[i][j2], 0, 0, 0);
    __syncthreads();
  }

#pragma unroll
  for (int j2 = 0; j2 < 4; ++j2) {
    const int n = n0 + wn * 64 + j2 * 16 + l15;
    const float bv = (n < NR) ? bias[n] : 0.f;
#pragma unroll
    for (int i = 0; i < 4; ++i) {
      const int mr = m0 + wm * 64 + i * 16 + quad * 4;
#pragma unroll
      for (int r = 0; r < 4; ++r) {
        float v = acc[i][j2][r] + bv;
        v = v > 0.f ? v : 0.f;
        H[(size_t)(mr + r) * NP + n] = (short)f2bf(v);
      }
    }
  }
}

// ---------------------------------------------------------------------------
// GEMM3: h2 bf16 [65536,512] x W3b [16,512] -> out f32 [65536,10]
// ---------------------------------------------------------------------------
__global__ __launch_bounds__(256, 2)
void gemm3_kernel(const short* __restrict__ Hin, const short* __restrict__ Wb,
                  const float* __restrict__ bias, float* __restrict__ Out) {
  constexpr int KP = 512;
  __shared__ short As[64 * KP];

  const int tid = threadIdx.x;
  const int lane = tid & 63;
  const int wave = tid >> 6;
  const int l15 = lane & 15;
  const int quad = lane >> 4;
  const int m0 = blockIdx.x * 64;

  bf16x8 bw[16];
#pragma unroll
  for (int kk = 0; kk < 16; ++kk)
    bw[kk] = *(const bf16x8*)(Wb + l15 * KP + kk * 32 + quad * 8);

  const short* asrc = Hin + (size_t)(m0 + wave * 16) * KP + lane * 8;
  short* adst = As + (size_t)(wave * 16) * KP;
#pragma unroll
  for (int t = 0; t < 16; ++t)
    glds16(asrc + (size_t)t * KP, adst + (size_t)t * KP);

  __syncthreads();

  f32x4 acc = (f32x4){0.f, 0.f, 0.f, 0.f};
  const short* abase = As + (size_t)(wave * 16 + l15) * KP + quad * 8;
#pragma unroll
  for (int kk = 0; kk < 16; ++kk) {
    bf16x8 af = *(const bf16x8*)(abase + kk * 32);
    acc = __builtin_amdgcn_mfma_f32_16x16x32_bf16(af, bw[kk], acc, 0, 0, 0);
  }

  if (l15 < 10) {
    const float bv = bias[l15];
#pragma unroll
    for (int r = 0; r < 4; ++r) {
      const int mr = m0 + wave * 16 + quad * 4 + r;
      Out[(size_t)mr * 10 + l15] = acc[r] + bv;
    }
  }
}

// ---------------------------------------------------------------------------
extern "C" void kernel_launch(void* const* d_in, const int* in_sizes, int n_in,
                              void* d_out, int out_size, void* d_ws, size_t ws_size,
                              hipStream_t stream) {
  const float* x = (const float*)d_in[0];
  const float* W1 = (const float*)d_in[1];
  const float* b1 = (const float*)d_in[2];
  const float* W2 = (const float*)d_in[3];
  const float* b2 = (const float*)d_in[4];
  const float* W3 = (const float*)d_in[5];
  const float* b3 = (const float*)d_in[6];
  float* out = (float*)d_out;

  const size_t szW1 = (size_t)1024 * 832 * 2;
  const size_t szW2 = (size_t)512 * 1024 * 2;
  const size_t szW3 = (size_t)16 * 512 * 2;
  const size_t szH1 = (size_t)65536 * 1024 * 2;
  const size_t szXp = (size_t)65536 * 832 * 2;  // shares Z with h2
  const size_t need = szW1 + szW2 + szW3 + szH1 + szXp;  // ~246 MB

  uint8_t* p = (uint8_t*)d_ws;
  short* W1b = (short*)p; p += szW1;
  short* W2b = (short*)p; p += szW2;
  short* W3b = (short*)p; p += szW3;
  short* h1 = (short*)p; p += szH1;
  short* Z = (short*)p;  // Xp (convert+gemm1), then h2 (gemm2+gemm3)

  binarize_kernel<<<(1024 * 832 + 255) / 256, 256, 0, stream>>>(W1, 1000, 784, W1b, 1024, 832);
  binarize_kernel<<<(512 * 1024 + 255) / 256, 256, 0, stream>>>(W2, 500, 1000, W2b, 512, 1024);
  binarize_kernel<<<(16 * 512 + 255) / 256, 256, 0, stream>>>(W3, 10, 500, W3b, 16, 512);

  if (ws_size >= need) {
    short* Xp = Z;
    short* h2 = Z;
    convert_x_kernel<<<(65536 * 104 + 255) / 256, 256, 0, stream>>>(x, Xp);
    gemm128x256<832, 26, 1024, 1000, 4><<<2048, 512, 0, stream>>>(Xp, W1b, b1, h1);
    gemm128x256<1024, 32, 512, 500, 2><<<1024, 512, 0, stream>>>(h1, W2b, b2, h2);
    gemm3_kernel<<<1024, 256, 0, stream>>>(h2, W3b, b3, out);
  } else {
    short* h2 = Z;
    gemm1_fused_kernel<<<dim3(8, 512), 256, 0, stream>>>(x, W1b, b1, h1);
    gemm128x256<1024, 32, 512, 500, 2><<<1024, 512, 0, stream>>>(h1, W2b, b2, h2);
    gemm3_kernel<<<1024, 256, 0, stream>>>(h2, W3b, b3, out);
  }
}

// Round 4
// 529.436 us; speedup vs baseline: 1.2692x; 1.0013x over previous
//
#include <hip/hip_runtime.h>
#include <stdint.h>

// ---------------------------------------------------------------------------
// Binary (sign) weight 3-layer MLP, round 10:
//   prep (ONE kernel): binarize W1,W2,W3 + convert x f32->bf16 [65536,832]
//   gemm1: h1 = relu(Xp @ sign(W1)^T + b1) -> bf16 [65536,1024]
//   gemm2: h2 = relu(h1 @ sign(W2)^T + b2) -> bf16 [65536,512]
//   gemm3: out = h2 @ sign(W3)^T + b3      -> f32  [65536,10]
// R10 vs R9 (R9: 530us, gemm1 144us @ MfmaUtil 33%, 2 barriers/iter):
//   1. TRIPLE-buffered K-loop -> stage(it+2) targets the buffer freed by
//      LAST iter's barrier => single [vmcnt(3); lgkm(0); s_barrier] cluster
//      per iteration (was: 2 barriers + mid-iter lgkm drain). LDS 72KB,
//      still 2 blocks/CU, VGPR unchanged (~56+64 AGPR).
//   2. prep kernels merged 4 -> 1 launch (saves ~30us of launch overhead).
//   Epilogue (j-innermost, WRITE=ideal) and swizzles kept from R9.
// ---------------------------------------------------------------------------

typedef __attribute__((ext_vector_type(8))) short bf16x8;
typedef __attribute__((ext_vector_type(4))) float f32x4;

typedef const __attribute__((address_space(1))) unsigned int* as1_u32p;
typedef __attribute__((address_space(3))) unsigned int* as3_u32p;

__device__ __forceinline__ void glds16(const void* g, void* l) {
  __builtin_amdgcn_global_load_lds((as1_u32p)g, (as3_u32p)l, 16, 0, 0);
}

__device__ __forceinline__ unsigned short f2bf(float f) {
  union { float f; unsigned u; } c;
  c.f = f;
  unsigned u = c.u;
  u += 0x7FFFu + ((u >> 16) & 1u);  // RTNE
  return (unsigned short)(u >> 16);
}

__device__ __forceinline__ void binarize_one(const float* __restrict__ src,
                                             int Ns, int Ks, short* __restrict__ dst,
                                             int Kp, int idx, int total) {
  if (idx >= total) return;
  int n = idx / Kp;
  int k = idx - n * Kp;
  short v = 0;
  if (n < Ns && k < Ks)
    v = (src[n * Ks + k] >= 0.0f) ? (short)0x3F80 : (short)0xBF80;
  dst[idx] = v;
}

// ---------------------------------------------------------------------------
// prep: [0,26624) convert_x | then binarize W1 (3328 blk) | W2 (2048) | W3 (32)
// ---------------------------------------------------------------------------
__global__ void prep_kernel(const float* __restrict__ X, short* __restrict__ Xp,
                            const float* __restrict__ W1, short* __restrict__ W1b,
                            const float* __restrict__ W2, short* __restrict__ W2b,
                            const float* __restrict__ W3, short* __restrict__ W3b) {
  constexpr int C0 = 26624;          // convert_x blocks (65536*104/256)
  constexpr int C1 = C0 + 3328;      // W1b: 1024*832
  constexpr int C2 = C1 + 2048;      // W2b: 512*1024
  const int bid = blockIdx.x;
  if (bid < C0) {
    const int g = bid * 256 + threadIdx.x;
    const int row = g / 104;
    const int c = (g - row * 104) * 8;
    short tmp[8];
    if (c < 784) {
      const float* s = X + (size_t)row * 784 + c;
      float4 f0 = *(const float4*)s;
      float4 f1 = *(const float4*)(s + 4);
      tmp[0] = (short)f2bf(f0.x); tmp[1] = (short)f2bf(f0.y);
      tmp[2] = (short)f2bf(f0.z); tmp[3] = (short)f2bf(f0.w);
      tmp[4] = (short)f2bf(f1.x); tmp[5] = (short)f2bf(f1.y);
      tmp[6] = (short)f2bf(f1.z); tmp[7] = (short)f2bf(f1.w);
    } else {
#pragma unroll
      for (int i = 0; i < 8; ++i) tmp[i] = 0;
    }
    *(bf16x8*)(Xp + (size_t)row * 832 + c) = *(bf16x8*)(tmp);
  } else if (bid < C1) {
    binarize_one(W1, 1000, 784, W1b, 832, (bid - C0) * 256 + threadIdx.x, 1024 * 832);
  } else if (bid < C2) {
    binarize_one(W2, 500, 1000, W2b, 1024, (bid - C1) * 256 + threadIdx.x, 512 * 1024);
  } else {
    binarize_one(W3, 10, 500, W3b, 512, (bid - C2) * 256 + threadIdx.x, 16 * 512);
  }
}

// ---------------------------------------------------------------------------
// 128(M) x 256(N) tile, BK=32, 8 waves (2M x 4N), wave out 64x64 (acc=64 AGPR).
// TRIPLE-buffered LDS: A[3][128*32] + B[3][256*32] = 72 KiB -> 2 blocks/CU.
// Per iter: stage(it+2) -> buf freed last iter; frag-read(it); 16 MFMA;
// [vmcnt(3); lgkm(0); barrier]  (ONE barrier, counted vmcnt, never 0 until tail).
// Swizzle: LDS[row][s] = global[row][s ^ ((row>>1)&3)], s = 8-short slot.
// ---------------------------------------------------------------------------
template <int KP, int NKT, int NP, int NR, int NT>
__global__ __launch_bounds__(512, 4)
void gemm128x256(const short* __restrict__ A, const short* __restrict__ Wb,
                 const float* __restrict__ bias, short* __restrict__ Hout) {
  __shared__ short Abuf[3][128 * 32];
  __shared__ short Bbuf[3][256 * 32];

  // XCD swizzle: grid = 512*NT blocks (divisible by 8 -> bijective).
  constexpr int NWG8 = (512 * NT) >> 3;
  const int d = blockIdx.x;
  const int lid = (d & 7) * NWG8 + (d >> 3);
  const int mi = lid / NT;
  const int ni = lid - mi * NT;
  const int m0 = mi << 7;
  const int n0 = ni << 8;
  const int start = (ni * NKT) / NT;  // K-phase rotation

  const int tid = threadIdx.x;
  const int lane = tid & 63;
  const int w = tid >> 6;   // 0..7
  const int wm = w >> 2;    // 0..1  (64 m-rows each)
  const int wn = w & 3;     // 0..3  (64 n-cols each)
  const int l15 = lane & 15;
  const int quad = lane >> 4;

  // --- staging addresses (pre-swizzled global source, linear LDS dest) ---
  const int srow = tid >> 2;                       // 0..127
  const int sslot = tid & 3;
  const int gcol = ((sslot ^ ((srow >> 1) & 3)) << 3);
  const short* ag = A + (size_t)(m0 + srow) * KP + gcol;
  const short* bg = Wb + (size_t)(n0 + srow) * KP + gcol;
  const int ldsw = w << 9;  // wave-uniform: w*512 shorts (16 rows * 32)

  auto stageA = [&](int pb, int kit) {
    glds16(ag + kit * 32, &Abuf[pb][ldsw]);
  };
  auto stageB = [&](int pb, int kit) {
    const short* s = bg + kit * 32;
    glds16(s, &Bbuf[pb][ldsw]);
    glds16(s + (size_t)128 * KP, &Bbuf[pb][ldsw + 4096]);
  };

  // --- fragment read offsets (swizzled slot; (row>>1)&3 == (l15>>1)&3) ---
  const int sl = (quad ^ ((l15 >> 1) & 3)) << 3;
  const int abase = ((wm << 6) + l15) * 32 + sl;   // + i*512
  const int bbase = ((wn << 6) + l15) * 32 + sl;   // + j*512

  f32x4 acc[4][4];
#pragma unroll
  for (int i = 0; i < 4; ++i)
#pragma unroll
    for (int j = 0; j < 4; ++j) acc[i][j] = (f32x4){0.f, 0.f, 0.f, 0.f};

  // --- prologue: stage tiles start -> buf0, start+1 -> buf1; confirm tile0 ---
  int kt1 = start + 1; if (kt1 >= NKT) kt1 -= NKT;
  stageA(0, start); stageB(0, start);
  stageA(1, kt1);   stageB(1, kt1);
  asm volatile("s_waitcnt vmcnt(3)" ::: "memory");  // tile start landed (mine)
  __builtin_amdgcn_s_barrier();                     // published to all waves

  int pb = 0;   // buffer holding tile it
  int tb = 2;   // stage target = (it+2)%3 (freed by last iter's barrier)
  int kit2 = start + 2; if (kit2 >= NKT) kit2 -= NKT;

  for (int it = 0; it < NKT; ++it) {
    // stage tile it+2 into the buffer freed last iteration
    if (it + 2 < NKT) { stageA(tb, kit2); stageB(tb, kit2); }

    const short* Ab = &Abuf[pb][0];
    const short* Bb = &Bbuf[pb][0];
    bf16x8 af[4], bf[4];
#pragma unroll
    for (int i = 0; i < 4; ++i) af[i] = *(const bf16x8*)(Ab + abase + i * 512);
#pragma unroll
    for (int j = 0; j < 4; ++j) bf[j] = *(const bf16x8*)(Bb + bbase + j * 512);

    __builtin_amdgcn_s_setprio(1);
#pragma unroll
    for (int i = 0; i < 4; ++i)
#pragma unroll
      for (int j = 0; j < 4; ++j)
        acc[i][j] = __builtin_amdgcn_mfma_f32_16x16x32_bf16(af[i], bf[j], acc[i][j], 0, 0, 0);
    __builtin_amdgcn_s_setprio(0);

    // single publish cluster: tile it+1 resident + buf[pb] free (all waves)
    if (it < NKT - 2) asm volatile("s_waitcnt vmcnt(3)" ::: "memory");
    else              asm volatile("s_waitcnt vmcnt(0)" ::: "memory");
    asm volatile("s_waitcnt lgkmcnt(0)" ::: "memory");
    __builtin_amdgcn_s_barrier();

    pb = (pb == 2) ? 0 : pb + 1;
    tb = (tb == 2) ? 0 : tb + 1;
    kit2 = kit2 + 1; if (kit2 >= NKT) kit2 -= NKT;
  }

  // --- epilogue: j-innermost so both 32B halves of each 64B line are
  // written in adjacent instructions (write-combine friendly) ---
  float bv[4];
#pragma unroll
  for (int j = 0; j < 4; ++j) {
    const int n = n0 + (wn << 6) + (j << 4) + l15;
    bv[j] = (n < NR) ? bias[n] : 0.f;
  }
#pragma unroll
  for (int i = 0; i < 4; ++i) {
#pragma unroll
    for (int r = 0; r < 4; ++r) {
      const int mr = m0 + (wm << 6) + (i << 4) + (quad << 2) + r;
      short* rowp = Hout + (size_t)mr * NP + n0 + (wn << 6) + l15;
#pragma unroll
      for (int j = 0; j < 4; ++j) {
        float v = acc[i][j][r] + bv[j];
        v = v > 0.f ? v : 0.f;
        rowp[j << 4] = (short)f2bf(v);
      }
    }
  }
}

// ---------------------------------------------------------------------------
// Fallback GEMM1 (small-ws): fused fp32->bf16 convert, 128-tile, BK=32.
// ---------------------------------------------------------------------------
__global__ __launch_bounds__(256, 2)
void gemm1_fused_kernel(const float* __restrict__ X, const short* __restrict__ Wb,
                        const float* __restrict__ bias, short* __restrict__ H) {
  constexpr int K = 784, KP = 832, NP = 1024, NR = 1000;
  __shared__ short As[128 * 32];
  __shared__ short Bs[128 * 32];

  const int tid = threadIdx.x;
  const int lane = tid & 63;
  const int wave = tid >> 6;
  const int wm = wave >> 1, wn = wave & 1;
  const int l15 = lane & 15;
  const int quad = lane >> 4;
  const int m0 = blockIdx.y * 128;
  const int n0 = blockIdx.x * 128;

  const int ar = tid >> 1;
  const int aks = (tid & 1) * 16;
  const float* xrow = X + (size_t)(m0 + ar) * K;
  short* adst = As + ar * 32 + aks;

  const int br = wave * 16 + (lane >> 2);
  const int bks = (lane & 3) * 8;
  const short* brow0 = Wb + (size_t)(n0 + br) * KP + bks;
  short* bdst = Bs + (wave * 16) * 32;

  f32x4 acc[4][4];
#pragma unroll
  for (int i = 0; i < 4; ++i)
#pragma unroll
    for (int j2 = 0; j2 < 4; ++j2) acc[i][j2] = (f32x4){0.f, 0.f, 0.f, 0.f};

  for (int k0 = 0; k0 < KP; k0 += 32) {
    glds16(brow0 + k0, bdst);
    glds16(brow0 + k0 + (size_t)64 * KP, bdst + 64 * 32);
    short tmp[16];
#pragma unroll
    for (int c = 0; c < 4; ++c) {
      const int kk = k0 + aks + c * 4;
      float4 f;
      if (kk + 3 < K)
        f = *(const float4*)(xrow + kk);
      else
        f = make_float4(0.f, 0.f, 0.f, 0.f);
      tmp[c * 4 + 0] = (short)f2bf(f.x);
      tmp[c * 4 + 1] = (short)f2bf(f.y);
      tmp[c * 4 + 2] = (short)f2bf(f.z);
      tmp[c * 4 + 3] = (short)f2bf(f.w);
    }
    *(bf16x8*)(adst) = *(bf16x8*)(tmp);
    *(bf16x8*)(adst + 8) = *(bf16x8*)(tmp + 8);
    __syncthreads();

    const short* abase = As + (size_t)(wm * 64 + l15) * 32 + quad * 8;
    const short* bbase = Bs + (size_t)(wn * 64 + l15) * 32 + quad * 8;
    bf16x8 af[4], bfr[4];
#pragma unroll
    for (int i = 0; i < 4; ++i) af[i] = *(const bf16x8*)(abase + i * 16 * 32);
#pragma unroll
    for (int j2 = 0; j2 < 4; ++j2) bfr[j2] = *(const bf16x8*)(bbase + j2 * 16 * 32);
#pragma unroll
    for (int i = 0; i < 4; ++i)
#pragma unroll
      for (int j2 = 0; j2 < 4; ++j2)
        acc[i][j2] = __builtin_amdgcn_mfma_f32_16x16x32_bf16(af[i], bfr[j2], acc[i][j2], 0, 0, 0);
    __syncthreads();
  }

#pragma unroll
  for (int j2 = 0; j2 < 4; ++j2) {
    const int n = n0 + wn * 64 + j2 * 16 + l15;
    const float bv = (n < NR) ? bias[n] : 0.f;
#pragma unroll
    for (int i = 0; i < 4; ++i) {
      const int mr = m0 + wm * 64 + i * 16 + quad * 4;
#pragma unroll
      for (int r = 0; r < 4; ++r) {
        float v = acc[i][j2][r] + bv;
        v = v > 0.f ? v : 0.f;
        H[(size_t)(mr + r) * NP + n] = (short)f2bf(v);
      }
    }
  }
}

// ---------------------------------------------------------------------------
// GEMM3: h2 bf16 [65536,512] x W3b [16,512] -> out f32 [65536,10]
// ---------------------------------------------------------------------------
__global__ __launch_bounds__(256, 2)
void gemm3_kernel(const short* __restrict__ Hin, const short* __restrict__ Wb,
                  const float* __restrict__ bias, float* __restrict__ Out) {
  constexpr int KP = 512;
  __shared__ short As[64 * KP];

  const int tid = threadIdx.x;
  const int lane = tid & 63;
  const int wave = tid >> 6;
  const int l15 = lane & 15;
  const int quad = lane >> 4;
  const int m0 = blockIdx.x * 64;

  bf16x8 bw[16];
#pragma unroll
  for (int kk = 0; kk < 16; ++kk)
    bw[kk] = *(const bf16x8*)(Wb + l15 * KP + kk * 32 + quad * 8);

  const short* asrc = Hin + (size_t)(m0 + wave * 16) * KP + lane * 8;
  short* adst = As + (size_t)(wave * 16) * KP;
#pragma unroll
  for (int t = 0; t < 16; ++t)
    glds16(asrc + (size_t)t * KP, adst + (size_t)t * KP);

  __syncthreads();

  f32x4 acc = (f32x4){0.f, 0.f, 0.f, 0.f};
  const short* abase = As + (size_t)(wave * 16 + l15) * KP + quad * 8;
#pragma unroll
  for (int kk = 0; kk < 16; ++kk) {
    bf16x8 af = *(const bf16x8*)(abase + kk * 32);
    acc = __builtin_amdgcn_mfma_f32_16x16x32_bf16(af, bw[kk], acc, 0, 0, 0);
  }

  if (l15 < 10) {
    const float bv = bias[l15];
#pragma unroll
    for (int r = 0; r < 4; ++r) {
      const int mr = m0 + wave * 16 + quad * 4 + r;
      Out[(size_t)mr * 10 + l15] = acc[r] + bv;
    }
  }
}

// ---------------------------------------------------------------------------
extern "C" void kernel_launch(void* const* d_in, const int* in_sizes, int n_in,
                              void* d_out, int out_size, void* d_ws, size_t ws_size,
                              hipStream_t stream) {
  const float* x = (const float*)d_in[0];
  const float* W1 = (const float*)d_in[1];
  const float* b1 = (const float*)d_in[2];
  const float* W2 = (const float*)d_in[3];
  const float* b2 = (const float*)d_in[4];
  const float* W3 = (const float*)d_in[5];
  const float* b3 = (const float*)d_in[6];
  float* out = (float*)d_out;

  const size_t szW1 = (size_t)1024 * 832 * 2;
  const size_t szW2 = (size_t)512 * 1024 * 2;
  const size_t szW3 = (size_t)16 * 512 * 2;
  const size_t szH1 = (size_t)65536 * 1024 * 2;
  const size_t szXp = (size_t)65536 * 832 * 2;  // shares Z with h2
  const size_t need = szW1 + szW2 + szW3 + szH1 + szXp;  // ~246 MB

  uint8_t* p = (uint8_t*)d_ws;
  short* W1b = (short*)p; p += szW1;
  short* W2b = (short*)p; p += szW2;
  short* W3b = (short*)p; p += szW3;
  short* h1 = (short*)p; p += szH1;
  short* Z = (short*)p;  // Xp (prep+gemm1), then h2 (gemm2+gemm3)

  if (ws_size >= need) {
    short* Xp = Z;
    short* h2 = Z;
    prep_kernel<<<26624 + 3328 + 2048 + 32, 256, 0, stream>>>(
        x, Xp, W1, W1b, W2, W2b, W3, W3b);
    gemm128x256<832, 26, 1024, 1000, 4><<<2048, 512, 0, stream>>>(Xp, W1b, b1, h1);
    gemm128x256<1024, 32, 512, 500, 2><<<1024, 512, 0, stream>>>(h1, W2b, b2, h2);
    gemm3_kernel<<<1024, 256, 0, stream>>>(h2, W3b, b3, out);
  } else {
    short* h2 = Z;
    prep_kernel<<<26624 + 3328 + 2048 + 32, 256, 0, stream>>>(
        x, Z /*unused Xp slot aliases h2; gemm1_fused reads X directly*/,
        W1, W1b, W2, W2b, W3, W3b);
    gemm1_fused_kernel<<<dim3(8, 512), 256, 0, stream>>>(x, W1b, b1, h1);
    gemm128x256<1024, 32, 512, 500, 2><<<1024, 512, 0, stream>>>(h1, W2b, b2, h2);
    gemm3_kernel<<<1024, 256, 0, stream>>>(h2, W3b, b3, out);
  }
}